// Round 14
// baseline (133.648 us; speedup 1.0000x reference)
//
#include <hip/hip_runtime.h>
#include <hip/hip_bf16.h>

typedef short bf16x8 __attribute__((ext_vector_type(8)));
typedef float f32x4 __attribute__((ext_vector_type(4)));
typedef _Float16 half4 __attribute__((ext_vector_type(4)));

__device__ __forceinline__ short f2bf(float f) {
    union { float f; unsigned u; } v; v.f = f;
    unsigned r = (v.u + 0x7FFFu + ((v.u >> 16) & 1u)) >> 16;
    return (short)r;
}

__device__ __forceinline__ float selu_f(float x) {
    const float scale = 1.0507009873554805f;
    const float sa = 1.0507009873554805f * 1.6732632423543772f;
    return x > 0.f ? scale * x : sa * (__expf(x) - 1.f);
}

// ---------------------------------------------------------------------------
// Kernel 1 (merged prep): blocks 0-511: cbias; 512-767: w1img; 768-783: wvec
// ---------------------------------------------------------------------------
__global__ void __launch_bounds__(512) prep_all_kernel(
    const float* __restrict__ c, const int* __restrict__ lat_idx,
    const int* __restrict__ lon_idx,
    const float* __restrict__ f2W1, const float* __restrict__ f2b1,
    const float* __restrict__ f2W2, const float* __restrict__ f2b2,
    const float* __restrict__ fW1, const float* __restrict__ fb1,
    const float* __restrict__ fW21, const float* __restrict__ fW22,
    short* __restrict__ w1img, _Float16* __restrict__ wvec,
    float* __restrict__ cbias)
{
    const int bid = blockIdx.x;
    const int t = threadIdx.x;

    if (bid < 512) {
        __shared__ int cells[64];
        __shared__ float ctraj[128];
        __shared__ float hbuf[256];
        __shared__ float ctrf[128];
        const int b = bid;

        if (t < 64) cells[t] = lat_idx[b * 64 + t] * 17 + lon_idx[b * 64 + t];
        __syncthreads();

        if (t < 128) {
            float s = 0.f;
            #pragma unroll 8
            for (int j = 0; j < 64; ++j) s += c[t * 289 + cells[j]];
            ctraj[t] = s * (1.f / 64.f);
        }
        __syncthreads();

        if (t < 256) {
            float acc = f2b1[t];
            #pragma unroll 8
            for (int i = 0; i < 128; ++i) acc += ctraj[i] * f2W1[i * 256 + t];
            hbuf[t] = selu_f(acc);
        }
        __syncthreads();

        if (t < 128) {
            float acc = f2b2[t];
            #pragma unroll 8
            for (int i = 0; i < 256; ++i) acc += hbuf[i] * f2W2[i * 128 + t];
            ctrf[t] = acc;
        }
        __syncthreads();

        float acc = fb1[t];
        #pragma unroll 8
        for (int i = 0; i < 128; ++i) acc += ctrf[i] * fW1[(256 + i) * 512 + t];
        cbias[b * 512 + t] = acc;
    } else if (bid < 768) {
        int I = (bid - 512) * 512 + t;        // 0..131071
        int e = I & 7;
        int lane = (I >> 3) & 63;
        int cg = (I >> 9) & 31;
        int kc = I >> 14;
        int col = cg * 16 + (lane & 15);
        int k = kc * 32 + ((lane >> 4) << 3) + e;
        w1img[I] = f2bf(fW1[k * 512 + col]);
    } else {
        int I = (bid - 768) * 512 + t;        // 0..8191
        int e = I & 3;
        int lane = (I >> 2) & 63;
        int nc = I >> 8;
        int l15 = lane & 15, hi = lane >> 4;
        int n = nc * 16 + hi * 4 + e;
        float v = (l15 == 0) ? fW21[n] : (l15 == 1 ? fW22[n] : 0.f);
        wvec[I] = (_Float16)v;
    }
}

// ---------------------------------------------------------------------------
// Kernel 2: fused GEMM (K=256) + selu + MFMA reduce — AMORTIZED variant.
// 1024 blocks (b x n-half, XCD-paired) x 512 threads (8 waves, 64x32 tiles).
// Each block processes ALL 4 s-subtiles of its b:
//   - B slice (16KB/wave) burst-loaded into registers ONCE, reused 4x.
//   - A double-buffered 2x32KB LDS; A(st+1) staged issue-early/write-late
//     in two halves (T14) so HBM/L3 latency hides under K-loop + epilogue
//     and peak registers stay <=128 (4 waves/SIMD, 2 blocks/CU).
//   - K-loop: pure {4 ds_read + 8 MFMA} x 8, zero global traffic.
// LDS: bufA 2x32KB @0 | redM 2KB @65536 | redV 2KB @67584 = 69632 B.
// ---------------------------------------------------------------------------
__global__ void __launch_bounds__(512, 4) fused_gemm_kernel(
    const float* __restrict__ rho, const short* __restrict__ w1img,
    const float* __restrict__ cbias, const _Float16* __restrict__ wvec,
    float* __restrict__ plmP, float* __restrict__ plvP)
{
    __shared__ __align__(16) char smem[69632];

    const int tid  = threadIdx.x;
    const int lane = tid & 63;
    const int w    = tid >> 6;      // 0..7
    const int l15  = lane & 15;
    const int hi   = lane >> 4;     // 0..3

    const int bid = blockIdx.x;
    const int nh  = (bid >> 3) & 1;                 // paired on same XCD
    const int b   = ((bid >> 4) << 3) | (bid & 7);  // bijective

    // ---- B burst: whole wave slice (32 cols x 256 k) in registers, once ----
    const char* bp = (const char*)w1img + (nh * 16 + w * 2) * 1024 + lane * 16;
    bf16x8 bAll[16];
    #pragma unroll
    for (int j = 0; j < 16; ++j)
        bAll[j] = *(const bf16x8*)(bp + (size_t)(j >> 1) * 32768 + (j & 1) * 1024);

    // A staging constants (same mapping as R9-R13, verified)
    const int kc_w = (tid >> 2) & 7;
    const int hi_w = tid & 3;
    const int sw_w = (tid >> 5) ^ (tid & 15);
    const float* srcB = rho + (size_t)(b * 256) * 256 + tid * 8;

    float* redM = (float*)(smem + 65536);   // [8][64]
    float* redV = (float*)(smem + 67584);   // [8][64]

    // ---- stage A(0) into buf0 ----
    {
        #pragma unroll
        for (int j = 0; j < 4; ++j) {
            float4 f0 = *(const float4*)(srcB + j * 4096);
            float4 f1 = *(const float4*)(srcB + j * 4096 + 4);
            union { bf16x8 h; unsigned u[4]; } pk;
            asm("v_cvt_pk_bf16_f32 %0, %1, %2" : "=v"(pk.u[0]) : "v"(f0.x), "v"(f0.y));
            asm("v_cvt_pk_bf16_f32 %0, %1, %2" : "=v"(pk.u[1]) : "v"(f0.z), "v"(f0.w));
            asm("v_cvt_pk_bf16_f32 %0, %1, %2" : "=v"(pk.u[2]) : "v"(f1.x), "v"(f1.y));
            asm("v_cvt_pk_bf16_f32 %0, %1, %2" : "=v"(pk.u[3]) : "v"(f1.z), "v"(f1.w));
            int slot = (kc_w * 4 + j) * 64 + hi_w * 16 + sw_w;
            *(bf16x8*)(smem + (slot << 4)) = pk.h;
        }
    }
    __syncthreads();

    #pragma unroll
    for (int st = 0; st < 4; ++st) {
        char* bufC = smem + (st & 1) * 32768;
        char* bufN = smem + ((st + 1) & 1) * 32768;
        const float* srcN = srcB + (st + 1) * 16384;

        // T14 half 1: issue first 16 floats of A(st+1) before the K-loop
        float4 fa0, fa1, fa2, fa3;
        if (st < 3) {
            fa0 = *(const float4*)(srcN);
            fa1 = *(const float4*)(srcN + 4);
            fa2 = *(const float4*)(srcN + 4096);
            fa3 = *(const float4*)(srcN + 4096 + 4);
        }

        f32x4 acc[2][4];
        #pragma unroll
        for (int nf = 0; nf < 2; ++nf)
            #pragma unroll
            for (int sf = 0; sf < 4; ++sf)
                acc[nf][sf] = (f32x4){0.f, 0.f, 0.f, 0.f};

        // ---- K-loop: pure LDS + MFMA ----
        #pragma unroll
        for (int kc = 0; kc < 8; ++kc) {
            const int sw_r = l15 ^ (((kc & 3) << 2) | hi);
            const char* ab = bufC + ((kc * 256 + hi * 16 + sw_r) << 4);
            bf16x8 aF[4];
            #pragma unroll
            for (int sf = 0; sf < 4; ++sf)
                aF[sf] = *(const bf16x8*)(ab + sf * 1024);
            #pragma unroll
            for (int nf = 0; nf < 2; ++nf)
                #pragma unroll
                for (int sf = 0; sf < 4; ++sf)
                    acc[nf][sf] = __builtin_amdgcn_mfma_f32_16x16x32_bf16(
                        bAll[kc * 2 + nf], aF[sf], acc[nf][sf], 0, 0, 0);
        }

        // T14: write half 1 to the OTHER buffer (no hazard), issue half 2
        float4 fb0, fb1v, fb2, fb3;
        if (st < 3) {
            {
                union { bf16x8 h; unsigned u[4]; } pk;
                asm("v_cvt_pk_bf16_f32 %0, %1, %2" : "=v"(pk.u[0]) : "v"(fa0.x), "v"(fa0.y));
                asm("v_cvt_pk_bf16_f32 %0, %1, %2" : "=v"(pk.u[1]) : "v"(fa0.z), "v"(fa0.w));
                asm("v_cvt_pk_bf16_f32 %0, %1, %2" : "=v"(pk.u[2]) : "v"(fa1.x), "v"(fa1.y));
                asm("v_cvt_pk_bf16_f32 %0, %1, %2" : "=v"(pk.u[3]) : "v"(fa1.z), "v"(fa1.w));
                int slot = (kc_w * 4 + 0) * 64 + hi_w * 16 + sw_w;
                *(bf16x8*)(bufN + (slot << 4)) = pk.h;
            }
            {
                union { bf16x8 h; unsigned u[4]; } pk;
                asm("v_cvt_pk_bf16_f32 %0, %1, %2" : "=v"(pk.u[0]) : "v"(fa2.x), "v"(fa2.y));
                asm("v_cvt_pk_bf16_f32 %0, %1, %2" : "=v"(pk.u[1]) : "v"(fa2.z), "v"(fa2.w));
                asm("v_cvt_pk_bf16_f32 %0, %1, %2" : "=v"(pk.u[2]) : "v"(fa3.x), "v"(fa3.y));
                asm("v_cvt_pk_bf16_f32 %0, %1, %2" : "=v"(pk.u[3]) : "v"(fa3.z), "v"(fa3.w));
                int slot = (kc_w * 4 + 1) * 64 + hi_w * 16 + sw_w;
                *(bf16x8*)(bufN + (slot << 4)) = pk.h;
            }
            fb0  = *(const float4*)(srcN + 2 * 4096);
            fb1v = *(const float4*)(srcN + 2 * 4096 + 4);
            fb2  = *(const float4*)(srcN + 3 * 4096);
            fb3  = *(const float4*)(srcN + 3 * 4096 + 4);
        }

        // ---- epilogue: selu(acc + cbias) -> f16 frags -> reduce MFMA ----
        f32x4 rd[4];
        #pragma unroll
        for (int sf = 0; sf < 4; ++sf) rd[sf] = (f32x4){0.f, 0.f, 0.f, 0.f};

        #pragma unroll
        for (int nf = 0; nf < 2; ++nf) {
            const int nc = nh * 16 + w * 2 + nf;
            f32x4 cbf = *(const f32x4*)(cbias + b * 512 + nc * 16 + hi * 4);
            half4 wv = *(const half4*)(wvec + (size_t)nc * 256 + lane * 4);
            #pragma unroll
            for (int sf = 0; sf < 4; ++sf) {
                half4 pa;
                #pragma unroll
                for (int q = 0; q < 4; ++q)
                    pa[q] = (_Float16)selu_f(acc[nf][sf][q] + cbf[q]);
                rd[sf] = __builtin_amdgcn_mfma_f32_16x16x16f16(pa, wv, rd[sf], 0, 0, 0);
            }
        }

        if (l15 == 0) {
            #pragma unroll
            for (int sf = 0; sf < 4; ++sf)
                *(f32x4*)&redM[w * 64 + sf * 16 + hi * 4] = rd[sf];
        } else if (l15 == 1) {
            #pragma unroll
            for (int sf = 0; sf < 4; ++sf)
                *(f32x4*)&redV[w * 64 + sf * 16 + hi * 4] = rd[sf];
        }

        __syncthreads();   // red complete

        // merge + store partials; meanwhile write A(st+1) half 2
        size_t obase = (size_t)nh * 131072 + (size_t)b * 256 + st * 64;
        if (tid < 64) {
            float s = 0.f;
            #pragma unroll
            for (int j = 0; j < 8; ++j) s += redM[j * 64 + tid];
            plmP[obase + tid] = s;
        } else if (tid < 128) {
            int rr = tid - 64;
            float s = 0.f;
            #pragma unroll
            for (int j = 0; j < 8; ++j) s += redV[j * 64 + rr];
            plvP[obase + rr] = s;
        }
        if (st < 3) {
            {
                union { bf16x8 h; unsigned u[4]; } pk;
                asm("v_cvt_pk_bf16_f32 %0, %1, %2" : "=v"(pk.u[0]) : "v"(fb0.x), "v"(fb0.y));
                asm("v_cvt_pk_bf16_f32 %0, %1, %2" : "=v"(pk.u[1]) : "v"(fb0.z), "v"(fb0.w));
                asm("v_cvt_pk_bf16_f32 %0, %1, %2" : "=v"(pk.u[2]) : "v"(fb1v.x), "v"(fb1v.y));
                asm("v_cvt_pk_bf16_f32 %0, %1, %2" : "=v"(pk.u[3]) : "v"(fb1v.z), "v"(fb1v.w));
                int slot = (kc_w * 4 + 2) * 64 + hi_w * 16 + sw_w;
                *(bf16x8*)(bufN + (slot << 4)) = pk.h;
            }
            {
                union { bf16x8 h; unsigned u[4]; } pk;
                asm("v_cvt_pk_bf16_f32 %0, %1, %2" : "=v"(pk.u[0]) : "v"(fb2.x), "v"(fb2.y));
                asm("v_cvt_pk_bf16_f32 %0, %1, %2" : "=v"(pk.u[1]) : "v"(fb2.z), "v"(fb2.w));
                asm("v_cvt_pk_bf16_f32 %0, %1, %2" : "=v"(pk.u[2]) : "v"(fb3.x), "v"(fb3.y));
                asm("v_cvt_pk_bf16_f32 %0, %1, %2" : "=v"(pk.u[3]) : "v"(fb3.z), "v"(fb3.w));
                int slot = (kc_w * 4 + 3) * 64 + hi_w * 16 + sw_w;
                *(bf16x8*)(bufN + (slot << 4)) = pk.h;
            }
        }
        __syncthreads();   // bufN fully written; red free for next st
    }
}

// ---------------------------------------------------------------------------
// Kernel 3: per-b logsumexp over S=256 (summing n-half partials) + outputs
// ---------------------------------------------------------------------------
__global__ void __launch_bounds__(64) finalize_kernel(
    const float* __restrict__ plmP, const float* __restrict__ plvP,
    const float* __restrict__ w, const float* __restrict__ l,
    const float* __restrict__ b21p, const float* __restrict__ b22p,
    float* __restrict__ out)
{
    const int b = blockIdx.x;
    const int lane = threadIdx.x;
    const float b21 = b21p[0], b22 = b22p[0];

    float a1[4], a2[4];
    float m1 = -1e30f, m2 = -1e30f;
    #pragma unroll
    for (int i = 0; i < 4; ++i) {
        int s = i * 64 + lane;
        int idx = b * 256 + s;
        float lw = logf(w[idx]);
        a1[i] = plmP[idx] + plmP[131072 + idx] + b21 + lw;
        a2[i] = plvP[idx] + plvP[131072 + idx] + b22 + 2.f * lw;
        m1 = fmaxf(m1, a1[i]);
        m2 = fmaxf(m2, a2[i]);
    }
    #pragma unroll
    for (int m = 1; m < 64; m <<= 1) {
        m1 = fmaxf(m1, __shfl_xor(m1, m));
        m2 = fmaxf(m2, __shfl_xor(m2, m));
    }
    float s1 = 0.f, s2 = 0.f;
    #pragma unroll
    for (int i = 0; i < 4; ++i) {
        s1 += expf(a1[i] - m1);
        s2 += expf(a2[i] - m2);
    }
    #pragma unroll
    for (int m = 1; m < 64; m <<= 1) {
        s1 += __shfl_xor(s1, m);
        s2 += __shfl_xor(s2, m);
    }
    if (lane == 0) {
        float lm_agg = m1 + logf(s1);
        float lv_agg = m2 + logf(s2);
        float logl = logf(l[b]);
        out[b]       = logl - lm_agg;
        out[512 + b] = logl - 3.f * lm_agg - lv_agg;
    }
}

extern "C" void kernel_launch(void* const* d_in, const int* in_sizes, int n_in,
                              void* d_out, int out_size, void* d_ws, size_t ws_size,
                              hipStream_t stream) {
    const float* rho     = (const float*)d_in[0];
    const float* c       = (const float*)d_in[1];
    const float* w       = (const float*)d_in[2];
    const float* l       = (const float*)d_in[3];
    // d_in[4] = roads (unused by the reference)
    const int*   lon_idx = (const int*)d_in[5];
    const int*   lat_idx = (const int*)d_in[6];
    const float* f2W1    = (const float*)d_in[7];
    const float* f2b1    = (const float*)d_in[8];
    const float* f2W2    = (const float*)d_in[9];
    const float* f2b2    = (const float*)d_in[10];
    const float* fW1     = (const float*)d_in[11];
    const float* fb1     = (const float*)d_in[12];
    const float* fW21    = (const float*)d_in[13];
    const float* fb21    = (const float*)d_in[14];
    const float* fW22    = (const float*)d_in[15];
    const float* fb22    = (const float*)d_in[16];
    float* out = (float*)d_out;

    char* ws = (char*)d_ws;
    float*     cbias = (float*)(ws);               // 1048576 B
    short*     w1img = (short*)(ws + 1048576);     //  262144 B
    float*     plmP  = (float*)(ws + 1310720);     // 1048576 B (2 halves)
    float*     plvP  = (float*)(ws + 2359296);     // 1048576 B (2 halves)
    _Float16*  wvec  = (_Float16*)(ws + 3407872);  //   16384 B

    prep_all_kernel<<<784, 512, 0, stream>>>(c, lat_idx, lon_idx,
                                             f2W1, f2b1, f2W2, f2b2,
                                             fW1, fb1, fW21, fW22,
                                             w1img, wvec, cbias);
    fused_gemm_kernel<<<1024, 512, 0, stream>>>(rho, w1img, cbias, wvec,
                                                plmP, plvP);
    finalize_kernel<<<512, 64, 0, stream>>>(plmP, plvP, w, l, fb21, fb22, out);
}

// Round 15
// 113.847 us; speedup vs baseline: 1.1739x; 1.1739x over previous
//
#include <hip/hip_runtime.h>
#include <hip/hip_bf16.h>

typedef short bf16x8 __attribute__((ext_vector_type(8)));
typedef float f32x4 __attribute__((ext_vector_type(4)));
typedef float f32x16 __attribute__((ext_vector_type(16)));

__device__ __forceinline__ short f2bf(float f) {
    union { float f; unsigned u; } v; v.f = f;
    unsigned r = (v.u + 0x7FFFu + ((v.u >> 16) & 1u)) >> 16;
    return (short)r;
}

__device__ __forceinline__ float selu_f(float x) {
    const float scale = 1.0507009873554805f;
    const float sa = 1.0507009873554805f * 1.6732632423543772f;
    return x > 0.f ? scale * x : sa * (__expf(x) - 1.f);
}

// ---------------------------------------------------------------------------
// Kernel 1 (merged prep): blocks 0-511: cbias; 512-767: w1img (32x32 layout)
// w1img32: A-operand frags for v_mfma_f32_32x32x16_bf16:
//   I = ((kk*16 + ng)*64 + lane)*8 + e  holds
//   W1[k = kk*16 + (lane>>5)*8 + e][n = ng*32 + (lane&31)]
//   (kk 0..15 k-chunks of 16, ng 0..15 n-groups of 32)
// ---------------------------------------------------------------------------
__global__ void __launch_bounds__(512) prep_all_kernel(
    const float* __restrict__ c, const int* __restrict__ lat_idx,
    const int* __restrict__ lon_idx,
    const float* __restrict__ f2W1, const float* __restrict__ f2b1,
    const float* __restrict__ f2W2, const float* __restrict__ f2b2,
    const float* __restrict__ fW1, const float* __restrict__ fb1,
    short* __restrict__ w1img, float* __restrict__ cbias)
{
    const int bid = blockIdx.x;
    const int t = threadIdx.x;

    if (bid < 512) {
        __shared__ int cells[64];
        __shared__ float ctraj[128];
        __shared__ float hbuf[256];
        __shared__ float ctrf[128];
        const int b = bid;

        if (t < 64) cells[t] = lat_idx[b * 64 + t] * 17 + lon_idx[b * 64 + t];
        __syncthreads();

        if (t < 128) {
            float s = 0.f;
            #pragma unroll 8
            for (int j = 0; j < 64; ++j) s += c[t * 289 + cells[j]];
            ctraj[t] = s * (1.f / 64.f);
        }
        __syncthreads();

        if (t < 256) {
            float acc = f2b1[t];
            #pragma unroll 8
            for (int i = 0; i < 128; ++i) acc += ctraj[i] * f2W1[i * 256 + t];
            hbuf[t] = selu_f(acc);
        }
        __syncthreads();

        if (t < 128) {
            float acc = f2b2[t];
            #pragma unroll 8
            for (int i = 0; i < 256; ++i) acc += hbuf[i] * f2W2[i * 128 + t];
            ctrf[t] = acc;
        }
        __syncthreads();

        float acc = fb1[t];
        #pragma unroll 8
        for (int i = 0; i < 128; ++i) acc += ctrf[i] * fW1[(256 + i) * 512 + t];
        cbias[b * 512 + t] = acc;
    } else {
        int I = (bid - 512) * 512 + t;        // 0..131071
        int e = I & 7;
        int lane = (I >> 3) & 63;
        int ng = (I >> 9) & 15;
        int kk = I >> 13;                     // 0..15
        int k = kk * 16 + ((lane >> 5) << 3) + e;
        int col = ng * 32 + (lane & 31);
        w1img[I] = f2bf(fW1[k * 512 + col]);
    }
}

// ---------------------------------------------------------------------------
// Kernel 2: fused GEMM (K=256) + selu + f32 dot epilogue — 32x32x16 MFMA.
// 2048 blocks (b x s-quarter) x 512 threads (8 waves, wave = 64s x 64n).
// Per wave: acc[si][ni] 2x2 f32x16 (64 regs); B (W1) reg-dbuf 1-deep;
// A (rho) in 32KB LDS as 32x32 B-operand frags, XOR-swizzled.
// K-loop: 16 chunks x {2 ds_read_b128 + 2 B-loads + 4 MFMA 32x32x16}.
// Epilogue: per-lane f32 selu+dot over n (no shuffles, no f16), LDS merge.
// ---------------------------------------------------------------------------
__global__ void __launch_bounds__(512, 4) fused_gemm_kernel(
    const float* __restrict__ rho, const short* __restrict__ w1img,
    const float* __restrict__ cbias, const float* __restrict__ fw21,
    const float* __restrict__ fw22,
    float* __restrict__ plm, float* __restrict__ plv)
{
    __shared__ __align__(16) char smA[40960];   // A 32KB | redM 4KB | redV 4KB

    const int tid  = threadIdx.x;
    const int lane = tid & 63;
    const int w    = tid >> 6;      // 0..7
    const int l31  = lane & 31;
    const int h    = lane >> 5;     // 0..1

    const int b  = blockIdx.x >> 2;
    const int s0 = (blockIdx.x & 3) << 6;

    // ---- stage A: coalesced reads -> cvt_pk -> 32x32-frag LDS (swizzled) ----
    // thread t, iter j: floats [j*4096 + t*8, +8) of the 64x256 f32 tile
    //   row = j*16 + (t>>5), k0 = (t&31)*8 -> kk=(t&31)>>1, khalf=t&1
    //   dest: si=j>>1, lane_dest=(khalf<<5) | ((j&1)*16 + (t>>5))
    {
        const float* src = rho + (size_t)(b * 256 + s0) * 256 + tid * 8;
        const int kk_w = (tid & 31) >> 1;
        const int h_w  = tid & 1;
        const int xw   = (kk_w & 7) << 4;
        #pragma unroll
        for (int j = 0; j < 4; ++j) {
            float4 f0 = *(const float4*)(src + j * 4096);
            float4 f1 = *(const float4*)(src + j * 4096 + 4);
            union { bf16x8 hh; unsigned u[4]; } pk;
            asm("v_cvt_pk_bf16_f32 %0, %1, %2" : "=v"(pk.u[0]) : "v"(f0.x), "v"(f0.y));
            asm("v_cvt_pk_bf16_f32 %0, %1, %2" : "=v"(pk.u[1]) : "v"(f0.z), "v"(f0.w));
            asm("v_cvt_pk_bf16_f32 %0, %1, %2" : "=v"(pk.u[2]) : "v"(f1.x), "v"(f1.y));
            asm("v_cvt_pk_bf16_f32 %0, %1, %2" : "=v"(pk.u[3]) : "v"(f1.z), "v"(f1.w));
            int si_w = j >> 1;
            int ld   = (h_w << 5) | ((j & 1) * 16 + (tid >> 5));
            int byte = ((((kk_w * 2 + si_w) * 64) + ld) << 4) ^ xw;
            *(bf16x8*)(smA + byte) = pk.hh;
        }
    }
    __syncthreads();   // only block-wide barrier before the epilogue

    f32x16 acc[2][2];   // [si][ni]: C rows=n (W1 as A-op), cols=s (rho as B-op)
    #pragma unroll
    for (int si = 0; si < 2; ++si)
        #pragma unroll
        for (int ni = 0; ni < 2; ++ni)
            acc[si][ni] = (f32x16)(0.f);

    // wave w owns n in [w*64, w*64+64): ng = w*2, w*2+1. Per-kk stride 16KB.
    const char* bp = (const char*)w1img + ((w * 2) * 64 + lane) * 16;

    bf16x8 wN0 = *(const bf16x8*)(bp);
    bf16x8 wN1 = *(const bf16x8*)(bp + 1024);

    #pragma unroll
    for (int kk = 0; kk < 16; ++kk) {
        bf16x8 wC0 = wN0, wC1 = wN1;
        if (kk < 15) {
            wN0 = *(const bf16x8*)(bp + (size_t)(kk + 1) * 16384);
            wN1 = *(const bf16x8*)(bp + (size_t)(kk + 1) * 16384 + 1024);
        }
        const int xr = (kk & 7) << 4;
        const int base = (((kk * 2) * 64 + lane) << 4) ^ xr;
        bf16x8 aF0 = *(const bf16x8*)(smA + base);
        bf16x8 aF1 = *(const bf16x8*)(smA + base + 1024);
        acc[0][0] = __builtin_amdgcn_mfma_f32_32x32x16_bf16(wC0, aF0, acc[0][0], 0, 0, 0);
        acc[0][1] = __builtin_amdgcn_mfma_f32_32x32x16_bf16(wC1, aF0, acc[0][1], 0, 0, 0);
        acc[1][0] = __builtin_amdgcn_mfma_f32_32x32x16_bf16(wC0, aF1, acc[1][0], 0, 0, 0);
        acc[1][1] = __builtin_amdgcn_mfma_f32_32x32x16_bf16(wC1, aF1, acc[1][1], 0, 0, 0);
    }

    // ---- epilogue: f32 selu + W21/W22 dot over this wave's 64 n's ----
    // acc reg r: n = w*64 + ni*32 + (r&3) + 8*(r>>2) + 4*h; s = s0 + si*32 + l31
    float mm0 = 0.f, mm1 = 0.f, vv0 = 0.f, vv1 = 0.f;
    #pragma unroll
    for (int ni = 0; ni < 2; ++ni) {
        #pragma unroll
        for (int q = 0; q < 4; ++q) {
            int n0 = w * 64 + ni * 32 + 8 * q + 4 * h;
            f32x4 cb  = *(const f32x4*)(cbias + b * 512 + n0);
            f32x4 w1r = *(const f32x4*)(fw21 + n0);
            f32x4 w2r = *(const f32x4*)(fw22 + n0);
            #pragma unroll
            for (int e = 0; e < 4; ++e) {
                float sA = selu_f(acc[0][ni][4 * q + e] + cb[e]);
                float sB = selu_f(acc[1][ni][4 * q + e] + cb[e]);
                mm0 += sA * w1r[e];
                vv0 += sA * w2r[e];
                mm1 += sB * w1r[e];
                vv1 += sB * w2r[e];
            }
        }
    }

    float* redM = (float*)(smA + 32768);   // [16][64]
    float* redV = (float*)(smA + 36864);   // [16][64]
    {
        int idx = (w * 2 + h) * 64;
        redM[idx + l31]      = mm0;
        redM[idx + 32 + l31] = mm1;
        redV[idx + l31]      = vv0;
        redV[idx + 32 + l31] = vv1;
    }

    __syncthreads();
    size_t obase = (size_t)b * 256 + s0;
    if (tid < 64) {
        float s = 0.f;
        #pragma unroll
        for (int j = 0; j < 16; ++j) s += redM[j * 64 + tid];
        plm[obase + tid] = s;
    } else if (tid < 128) {
        int rr = tid - 64;
        float s = 0.f;
        #pragma unroll
        for (int j = 0; j < 16; ++j) s += redV[j * 64 + rr];
        plv[obase + rr] = s;
    }
}

// ---------------------------------------------------------------------------
// Kernel 3: per-b logsumexp over S=256 and final outputs (1 wave per b)
// ---------------------------------------------------------------------------
__global__ void __launch_bounds__(64) finalize_kernel(
    const float* __restrict__ plm, const float* __restrict__ plv,
    const float* __restrict__ w, const float* __restrict__ l,
    const float* __restrict__ b21p, const float* __restrict__ b22p,
    float* __restrict__ out)
{
    const int b = blockIdx.x;
    const int lane = threadIdx.x;
    const float b21 = b21p[0], b22 = b22p[0];

    float a1[4], a2[4];
    float m1 = -1e30f, m2 = -1e30f;
    #pragma unroll
    for (int i = 0; i < 4; ++i) {
        int s = i * 64 + lane;
        float lw = logf(w[b * 256 + s]);
        a1[i] = plm[b * 256 + s] + b21 + lw;
        a2[i] = plv[b * 256 + s] + b22 + 2.f * lw;
        m1 = fmaxf(m1, a1[i]);
        m2 = fmaxf(m2, a2[i]);
    }
    #pragma unroll
    for (int m = 1; m < 64; m <<= 1) {
        m1 = fmaxf(m1, __shfl_xor(m1, m));
        m2 = fmaxf(m2, __shfl_xor(m2, m));
    }
    float s1 = 0.f, s2 = 0.f;
    #pragma unroll
    for (int i = 0; i < 4; ++i) {
        s1 += expf(a1[i] - m1);
        s2 += expf(a2[i] - m2);
    }
    #pragma unroll
    for (int m = 1; m < 64; m <<= 1) {
        s1 += __shfl_xor(s1, m);
        s2 += __shfl_xor(s2, m);
    }
    if (lane == 0) {
        float lm_agg = m1 + logf(s1);
        float lv_agg = m2 + logf(s2);
        float logl = logf(l[b]);
        out[b]       = logl - lm_agg;
        out[512 + b] = logl - 3.f * lm_agg - lv_agg;
    }
}

extern "C" void kernel_launch(void* const* d_in, const int* in_sizes, int n_in,
                              void* d_out, int out_size, void* d_ws, size_t ws_size,
                              hipStream_t stream) {
    const float* rho     = (const float*)d_in[0];
    const float* c       = (const float*)d_in[1];
    const float* w       = (const float*)d_in[2];
    const float* l       = (const float*)d_in[3];
    // d_in[4] = roads (unused by the reference)
    const int*   lon_idx = (const int*)d_in[5];
    const int*   lat_idx = (const int*)d_in[6];
    const float* f2W1    = (const float*)d_in[7];
    const float* f2b1    = (const float*)d_in[8];
    const float* f2W2    = (const float*)d_in[9];
    const float* f2b2    = (const float*)d_in[10];
    const float* fW1     = (const float*)d_in[11];
    const float* fb1     = (const float*)d_in[12];
    const float* fW21    = (const float*)d_in[13];
    const float* fb21    = (const float*)d_in[14];
    const float* fW22    = (const float*)d_in[15];
    const float* fb22    = (const float*)d_in[16];
    float* out = (float*)d_out;

    char* ws = (char*)d_ws;
    float*     cbias = (float*)(ws);               // 1048576 B
    short*     w1img = (short*)(ws + 1048576);     //  262144 B
    float*     plm   = (float*)(ws + 1310720);     //  524288 B
    float*     plv   = (float*)(ws + 1835008);     //  524288 B

    prep_all_kernel<<<768, 512, 0, stream>>>(c, lat_idx, lon_idx,
                                             f2W1, f2b1, f2W2, f2b2,
                                             fW1, fb1, w1img, cbias);
    fused_gemm_kernel<<<2048, 512, 0, stream>>>(rho, w1img, cbias, fW21, fW22,
                                                plm, plv);
    finalize_kernel<<<512, 64, 0, stream>>>(plm, plv, w, l, fb21, fb22, out);
}

// Round 16
// 91.800 us; speedup vs baseline: 1.4559x; 1.2402x over previous
//
#include <hip/hip_runtime.h>
#include <hip/hip_bf16.h>

typedef short bf16x8 __attribute__((ext_vector_type(8)));
typedef float f32x4 __attribute__((ext_vector_type(4)));
typedef _Float16 half4 __attribute__((ext_vector_type(4)));

__device__ __forceinline__ short f2bf(float f) {
    union { float f; unsigned u; } v; v.f = f;
    unsigned r = (v.u + 0x7FFFu + ((v.u >> 16) & 1u)) >> 16;
    return (short)r;
}

__device__ __forceinline__ float selu_f(float x) {
    const float scale = 1.0507009873554805f;
    const float sa = 1.0507009873554805f * 1.6732632423543772f;
    return x > 0.f ? scale * x : sa * (__expf(x) - 1.f);
}

// ---------------------------------------------------------------------------
// Kernel 1 (merged prep): blocks 0-511: cbias; 512-767: w1img; 768-783: wvec
// ---------------------------------------------------------------------------
__global__ void __launch_bounds__(512) prep_all_kernel(
    const float* __restrict__ c, const int* __restrict__ lat_idx,
    const int* __restrict__ lon_idx,
    const float* __restrict__ f2W1, const float* __restrict__ f2b1,
    const float* __restrict__ f2W2, const float* __restrict__ f2b2,
    const float* __restrict__ fW1, const float* __restrict__ fb1,
    const float* __restrict__ fW21, const float* __restrict__ fW22,
    short* __restrict__ w1img, _Float16* __restrict__ wvec,
    float* __restrict__ cbias)
{
    const int bid = blockIdx.x;
    const int t = threadIdx.x;

    if (bid < 512) {
        __shared__ int cells[64];
        __shared__ float ctraj[128];
        __shared__ float hbuf[256];
        __shared__ float ctrf[128];
        const int b = bid;

        if (t < 64) cells[t] = lat_idx[b * 64 + t] * 17 + lon_idx[b * 64 + t];
        __syncthreads();

        if (t < 128) {
            float s = 0.f;
            #pragma unroll 8
            for (int j = 0; j < 64; ++j) s += c[t * 289 + cells[j]];
            ctraj[t] = s * (1.f / 64.f);
        }
        __syncthreads();

        if (t < 256) {
            float acc = f2b1[t];
            #pragma unroll 8
            for (int i = 0; i < 128; ++i) acc += ctraj[i] * f2W1[i * 256 + t];
            hbuf[t] = selu_f(acc);
        }
        __syncthreads();

        if (t < 128) {
            float acc = f2b2[t];
            #pragma unroll 8
            for (int i = 0; i < 256; ++i) acc += hbuf[i] * f2W2[i * 128 + t];
            ctrf[t] = acc;
        }
        __syncthreads();

        float acc = fb1[t];
        #pragma unroll 8
        for (int i = 0; i < 128; ++i) acc += ctrf[i] * fW1[(256 + i) * 512 + t];
        cbias[b * 512 + t] = acc;
    } else if (bid < 768) {
        int I = (bid - 512) * 512 + t;        // 0..131071
        int e = I & 7;
        int lane = (I >> 3) & 63;
        int cg = (I >> 9) & 31;
        int kc = I >> 14;
        int col = cg * 16 + (lane & 15);
        int k = kc * 32 + ((lane >> 4) << 3) + e;
        w1img[I] = f2bf(fW1[k * 512 + col]);
    } else {
        int I = (bid - 768) * 512 + t;        // 0..8191
        int e = I & 3;
        int lane = (I >> 2) & 63;
        int nc = I >> 8;
        int l15 = lane & 15, hi = lane >> 4;
        int n = nc * 16 + hi * 4 + e;
        float v = (l15 == 0) ? fW21[n] : (l15 == 1 ? fW22[n] : 0.f);
        wvec[I] = (_Float16)v;
    }
}

// ---------------------------------------------------------------------------
// Kernel 2: fused GEMM (K=256) + selu + MFMA reduce (best-measured config).
// 2048 blocks (b x s-quarter) x 512 threads (8 waves, each 64 rows x 64 cols
// of the 64x512 block tile; all waves share the A rows).
// A: staged once (coalesced 32B/lane reads -> cvt_pk -> XOR-swizzled
//    fragment-major LDS, conflict-free both sides); one barrier.
// B: per-wave global reg-dbuf (1-deep) from the L2-resident image.
// Zero barriers in the K-loop. f16-MFMA reduce epilogue (no shuffles).
// Registers: 64 VGPR + 64 AGPR = exactly the (512,4) cap — do not add state.
// ---------------------------------------------------------------------------
__global__ void __launch_bounds__(512, 4) fused_gemm_kernel(
    const float* __restrict__ rho, const short* __restrict__ w1img,
    const float* __restrict__ cbias, const _Float16* __restrict__ wvec,
    float* __restrict__ plm, float* __restrict__ plv)
{
    __shared__ __align__(16) char smA[36864];   // A 32KB | redM 2KB | redV 2KB

    const int tid  = threadIdx.x;
    const int lane = tid & 63;
    const int w    = tid >> 6;      // 0..7
    const int l15  = lane & 15;
    const int hi   = lane >> 4;     // 0..3

    const int b  = blockIdx.x >> 2;
    const int s0 = (blockIdx.x & 3) << 6;

    // ---- stage A once: coalesced reads -> cvt_pk -> swizzled frag-major ----
    {
        const float* src = rho + (size_t)(b * 256 + s0) * 256 + tid * 8;
        const int kc_w = (tid >> 2) & 7;
        const int hi_w = tid & 3;
        const int sw_w = (tid >> 5) ^ (tid & 15);
        #pragma unroll
        for (int j = 0; j < 4; ++j) {
            float4 f0 = *(const float4*)(src + j * 4096);
            float4 f1 = *(const float4*)(src + j * 4096 + 4);
            union { bf16x8 h; unsigned u[4]; } pk;
            asm("v_cvt_pk_bf16_f32 %0, %1, %2" : "=v"(pk.u[0]) : "v"(f0.x), "v"(f0.y));
            asm("v_cvt_pk_bf16_f32 %0, %1, %2" : "=v"(pk.u[1]) : "v"(f0.z), "v"(f0.w));
            asm("v_cvt_pk_bf16_f32 %0, %1, %2" : "=v"(pk.u[2]) : "v"(f1.x), "v"(f1.y));
            asm("v_cvt_pk_bf16_f32 %0, %1, %2" : "=v"(pk.u[3]) : "v"(f1.z), "v"(f1.w));
            int slot = (kc_w * 4 + j) * 64 + hi_w * 16 + sw_w;
            *(bf16x8*)(smA + (slot << 4)) = pk.h;
        }
    }
    __syncthreads();   // only block-wide barrier before the epilogue

    f32x4 acc[4][4];   // [nf][sf] (C^T, swapped operands)
    #pragma unroll
    for (int nf = 0; nf < 4; ++nf)
        #pragma unroll
        for (int sf = 0; sf < 4; ++sf)
            acc[nf][sf] = (f32x4){0.f, 0.f, 0.f, 0.f};

    // wave w owns cols w*64..w*64+63: col-groups cg = kc*32 + w*4 + nf
    const char* bp = (const char*)w1img + w * 4096 + lane * 16;

    bf16x8 bN[4];
    #pragma unroll
    for (int nf = 0; nf < 4; ++nf)
        bN[nf] = *(const bf16x8*)(bp + nf * 1024);

    #pragma unroll
    for (int kc = 0; kc < 8; ++kc) {
        bf16x8 bC[4];
        #pragma unroll
        for (int nf = 0; nf < 4; ++nf) bC[nf] = bN[nf];
        if (kc < 7) {
            #pragma unroll
            for (int nf = 0; nf < 4; ++nf)
                bN[nf] = *(const bf16x8*)(bp + (size_t)(kc + 1) * 32768 + nf * 1024);
        }
        // swizzled A-fragment reads (conflict-free)
        const int sw_r = l15 ^ (((kc & 3) << 2) | hi);
        const char* ab = smA + ((kc * 256 + hi * 16 + sw_r) << 4);
        bf16x8 aF[4];
        #pragma unroll
        for (int sf = 0; sf < 4; ++sf)
            aF[sf] = *(const bf16x8*)(ab + sf * 1024);
        #pragma unroll
        for (int nf = 0; nf < 4; ++nf)
            #pragma unroll
            for (int sf = 0; sf < 4; ++sf)
                acc[nf][sf] = __builtin_amdgcn_mfma_f32_16x16x32_bf16(
                    bC[nf], aF[sf], acc[nf][sf], 0, 0, 0);
    }

    // ---- epilogue: selu(acc + cbias) -> f16 frags -> 16x16x16 reduce MFMA ----
    f32x4 rd[4];
    #pragma unroll
    for (int sf = 0; sf < 4; ++sf) rd[sf] = (f32x4){0.f, 0.f, 0.f, 0.f};

    #pragma unroll
    for (int nf = 0; nf < 4; ++nf) {
        f32x4 cbf = *(const f32x4*)(cbias + b * 512 + w * 64 + nf * 16 + hi * 4);
        half4 wv = *(const half4*)(wvec + (size_t)(w * 4 + nf) * 256 + lane * 4);
        #pragma unroll
        for (int sf = 0; sf < 4; ++sf) {
            half4 pa;
            #pragma unroll
            for (int q = 0; q < 4; ++q)
                pa[q] = (_Float16)selu_f(acc[nf][sf][q] + cbf[q]);
            rd[sf] = __builtin_amdgcn_mfma_f32_16x16x16f16(pa, wv, rd[sf], 0, 0, 0);
        }
    }

    float* redM = (float*)(smA + 32768);   // [8][64]
    float* redV = (float*)(smA + 34816);   // [8][64]
    if (l15 == 0) {
        #pragma unroll
        for (int sf = 0; sf < 4; ++sf)
            *(f32x4*)&redM[w * 64 + sf * 16 + hi * 4] = rd[sf];
    } else if (l15 == 1) {
        #pragma unroll
        for (int sf = 0; sf < 4; ++sf)
            *(f32x4*)&redV[w * 64 + sf * 16 + hi * 4] = rd[sf];
    }

    __syncthreads();
    size_t obase = (size_t)b * 256 + s0;
    if (tid < 64) {
        float s = 0.f;
        #pragma unroll
        for (int j = 0; j < 8; ++j) s += redM[j * 64 + tid];
        plm[obase + tid] = s;
    } else if (tid < 128) {
        int rr = tid - 64;
        float s = 0.f;
        #pragma unroll
        for (int j = 0; j < 8; ++j) s += redV[j * 64 + rr];
        plv[obase + rr] = s;
    }
}

// ---------------------------------------------------------------------------
// Kernel 3: per-b logsumexp over S=256 and final outputs (1 wave per b)
// ---------------------------------------------------------------------------
__global__ void __launch_bounds__(64) finalize_kernel(
    const float* __restrict__ plm, const float* __restrict__ plv,
    const float* __restrict__ w, const float* __restrict__ l,
    const float* __restrict__ b21p, const float* __restrict__ b22p,
    float* __restrict__ out)
{
    const int b = blockIdx.x;
    const int lane = threadIdx.x;
    const float b21 = b21p[0], b22 = b22p[0];

    float a1[4], a2[4];
    float m1 = -1e30f, m2 = -1e30f;
    #pragma unroll
    for (int i = 0; i < 4; ++i) {
        int s = i * 64 + lane;
        float lw = logf(w[b * 256 + s]);
        a1[i] = plm[b * 256 + s] + b21 + lw;
        a2[i] = plv[b * 256 + s] + b22 + 2.f * lw;
        m1 = fmaxf(m1, a1[i]);
        m2 = fmaxf(m2, a2[i]);
    }
    #pragma unroll
    for (int m = 1; m < 64; m <<= 1) {
        m1 = fmaxf(m1, __shfl_xor(m1, m));
        m2 = fmaxf(m2, __shfl_xor(m2, m));
    }
    float s1 = 0.f, s2 = 0.f;
    #pragma unroll
    for (int i = 0; i < 4; ++i) {
        s1 += expf(a1[i] - m1);
        s2 += expf(a2[i] - m2);
    }
    #pragma unroll
    for (int m = 1; m < 64; m <<= 1) {
        s1 += __shfl_xor(s1, m);
        s2 += __shfl_xor(s2, m);
    }
    if (lane == 0) {
        float lm_agg = m1 + logf(s1);
        float lv_agg = m2 + logf(s2);
        float logl = logf(l[b]);
        out[b]       = logl - lm_agg;
        out[512 + b] = logl - 3.f * lm_agg - lv_agg;
    }
}

extern "C" void kernel_launch(void* const* d_in, const int* in_sizes, int n_in,
                              void* d_out, int out_size, void* d_ws, size_t ws_size,
                              hipStream_t stream) {
    const float* rho     = (const float*)d_in[0];
    const float* c       = (const float*)d_in[1];
    const float* w       = (const float*)d_in[2];
    const float* l       = (const float*)d_in[3];
    // d_in[4] = roads (unused by the reference)
    const int*   lon_idx = (const int*)d_in[5];
    const int*   lat_idx = (const int*)d_in[6];
    const float* f2W1    = (const float*)d_in[7];
    const float* f2b1    = (const float*)d_in[8];
    const float* f2W2    = (const float*)d_in[9];
    const float* f2b2    = (const float*)d_in[10];
    const float* fW1     = (const float*)d_in[11];
    const float* fb1     = (const float*)d_in[12];
    const float* fW21    = (const float*)d_in[13];
    const float* fb21    = (const float*)d_in[14];
    const float* fW22    = (const float*)d_in[15];
    const float* fb22    = (const float*)d_in[16];
    float* out = (float*)d_out;

    char* ws = (char*)d_ws;
    float*     cbias = (float*)(ws);               // 1048576 B
    short*     w1img = (short*)(ws + 1048576);     //  262144 B
    float*     plm   = (float*)(ws + 1310720);     //  524288 B
    float*     plv   = (float*)(ws + 1835008);     //  524288 B
    _Float16*  wvec  = (_Float16*)(ws + 2359296);  //   16384 B

    prep_all_kernel<<<784, 512, 0, stream>>>(c, lat_idx, lon_idx,
                                             f2W1, f2b1, f2W2, f2b2,
                                             fW1, fb1, fW21, fW22,
                                             w1img, wvec, cbias);
    fused_gemm_kernel<<<2048, 512, 0, stream>>>(rho, w1img, cbias, wvec,
                                                plm, plv);
    finalize_kernel<<<512, 64, 0, stream>>>(plm, plv, w, l, fb21, fb22, out);
}